// Round 2
// baseline (110.735 us; speedup 1.0000x reference)
//
#include <hip/hip_runtime.h>
#include <hip/hip_bf16.h>

// CharRNN: B=16384, T=100, V=256, E=50, H=10, L=15 — ALL float tensors fp32.
// Inputs: x(int32 [B,T]), emb(f32 [V,E]), Wx(f32 [E,H]), Wh(f32 [H,H]),
//         b_rnn(f32 [H]), Wd(f32 [H,L]), bd(f32 [L]), drop_mask(f32 [B,H])
// Output: logits fp32 [B,L]
//
// Strategy: precompute P[v][j] = emb[v]·Wx[:,j] + b_rnn[j] (256x12-padded
// fp32 table) -> recurrence is h = tanh(P[x_t] + h@Wh): 50 pk-FMA + 10 tanh
// per step per batch element. One thread per batch element.

#define Bn 16384
#define Tn 100
#define Vn 256
#define En 50
#define Hn 10
#define Ln 15
#define PROW 12  // padded P row length in floats (48B, 16B-aligned rows)

typedef float v2f __attribute__((ext_vector_type(2)));

__device__ __forceinline__ float tanh_fast(float x) {
    // tanh(x) = 1 - 2/(exp2(2x/ln2) + 1); clamp so exp can't overflow.
    float xc = fminf(fmaxf(x, -8.f), 8.f);
    float e  = __builtin_amdgcn_exp2f(xc * 2.8853900817779268f);
    float r  = __builtin_amdgcn_rcpf(e + 1.f);
    return __builtin_fmaf(-2.f, r, 1.f);
}

// Kernel 1: build P table in workspace (fp32). Thread = (v, j) over V*PROW.
__global__ void precompute_P(const float* __restrict__ emb,
                             const float* __restrict__ Wx,
                             const float* __restrict__ b_rnn,
                             float* __restrict__ P) {
    int tid = blockIdx.x * blockDim.x + threadIdx.x;
    if (tid >= Vn * PROW) return;
    int v = tid / PROW, j = tid - v * PROW;
    float acc = 0.f;
    if (j < Hn) {
        acc = b_rnn[j];
        #pragma unroll 5
        for (int k = 0; k < En; ++k)
            acc = __builtin_fmaf(emb[v * En + k], Wx[k * Hn + j], acc);
    }
    P[tid] = acc;  // pads (j>=10) written as 0 every launch (ws is re-poisoned)
}

// Kernel 2: the recurrence. One thread per batch element.
__global__ __launch_bounds__(64) void rnn_fwd(
    const int* __restrict__ x,
    const float* __restrict__ P,
    const float* __restrict__ Wh,
    const float* __restrict__ Wd,
    const float* __restrict__ bd,
    const float* __restrict__ drop,
    float* __restrict__ out) {
    __shared__ float Pl[Vn * PROW];  // 12 KB

    // Stage P (global fp32 -> LDS), 768 float4 across 64 threads.
    {
        const float4* Pg = (const float4*)P;
        float4* Ps = (float4*)Pl;
        #pragma unroll
        for (int i = 0; i < (Vn * PROW / 4) / 64; ++i)
            Ps[i * 64 + threadIdx.x] = Pg[i * 64 + threadIdx.x];
    }

    // Wh into registers as packed float2 pairs: wh2[k][j2] = Wh[k][2j2..2j2+1]
    v2f wh2[Hn][Hn / 2];
    #pragma unroll
    for (int k = 0; k < Hn; ++k)
        #pragma unroll
        for (int j2 = 0; j2 < Hn / 2; ++j2) {
            v2f w;
            w.x = Wh[k * Hn + 2 * j2];
            w.y = Wh[k * Hn + 2 * j2 + 1];
            wh2[k][j2] = w;
        }
    __syncthreads();

    const int b = blockIdx.x * 64 + threadIdx.x;
    const int* xb = x + b * Tn;  // b*400 bytes -> 16B aligned

    float h[Hn];
    #pragma unroll
    for (int j = 0; j < Hn; ++j) h[j] = 0.f;

    int4 xi = *(const int4*)xb;  // prefetched chunk of 4 timesteps
    for (int c = 0; c < Tn / 4; ++c) {
        int4 xin = (c + 1 < Tn / 4) ? ((const int4*)xb)[c + 1] : xi;
        int xs[4] = {xi.x, xi.y, xi.z, xi.w};
        #pragma unroll
        for (int u = 0; u < 4; ++u) {
            const float* Pr = &Pl[xs[u] * PROW];
            v2f pre2[Hn / 2];
            #pragma unroll
            for (int j2 = 0; j2 < Hn / 2; ++j2) {
                v2f p;
                p.x = Pr[2 * j2];
                p.y = Pr[2 * j2 + 1];
                pre2[j2] = p;
            }
            #pragma unroll
            for (int k = 0; k < Hn; ++k) {
                v2f hk = {h[k], h[k]};
                #pragma unroll
                for (int j2 = 0; j2 < Hn / 2; ++j2)
                    pre2[j2] += hk * wh2[k][j2];
            }
            #pragma unroll
            for (int j2 = 0; j2 < Hn / 2; ++j2) {
                h[2 * j2]     = tanh_fast(pre2[j2].x);
                h[2 * j2 + 1] = tanh_fast(pre2[j2].y);
            }
        }
        xi = xin;
    }

    // Epilogue: dropout + dense layer, write fp32.
    float logit[Ln];
    #pragma unroll
    for (int l = 0; l < Ln; ++l) logit[l] = bd[l];
    #pragma unroll
    for (int j = 0; j < Hn; ++j) {
        float hd = h[j] * drop[b * Hn + j];
        #pragma unroll
        for (int l = 0; l < Ln; ++l)
            logit[l] = __builtin_fmaf(hd, Wd[j * Ln + l], logit[l]);
    }
    #pragma unroll
    for (int l = 0; l < Ln; ++l) out[b * Ln + l] = logit[l];
}

extern "C" void kernel_launch(void* const* d_in, const int* in_sizes, int n_in,
                              void* d_out, int out_size, void* d_ws, size_t ws_size,
                              hipStream_t stream) {
    const int*   x      = (const int*)d_in[0];
    const float* emb    = (const float*)d_in[1];
    const float* Wx     = (const float*)d_in[2];
    const float* Wh     = (const float*)d_in[3];
    const float* b_rnn  = (const float*)d_in[4];
    const float* Wd     = (const float*)d_in[5];
    const float* bd     = (const float*)d_in[6];
    const float* drop   = (const float*)d_in[7];
    float*       out    = (float*)d_out;

    float* P = (float*)d_ws;  // Vn*PROW*4 = 12288 bytes

    precompute_P<<<(Vn * PROW + 255) / 256, 256, 0, stream>>>(emb, Wx, b_rnn, P);
    rnn_fwd<<<Bn / 64, 64, 0, stream>>>(x, P, Wh, Wd, bd, drop, out);
}

// Round 3
// 90.970 us; speedup vs baseline: 1.2173x; 1.2173x over previous
//
#include <hip/hip_runtime.h>
#include <hip/hip_bf16.h>

// CharRNN: B=16384, T=100, V=256, E=50, H=10, L=15 — float tensors fp32.
// R3 strategy: P-table factorization (as R2) + quad-lane split of the
// recurrence: each batch element is handled by 4 consecutive lanes, each
// owning 3 of the 12 (zero-padded) hidden units. Per-step h exchange via
// DPP quad_perm (full-rate VALU, no LDS pipe). 1024 waves -> 1 wave per
// SIMD on all 1024 SIMDs (R2 used only 256).

#define Bn 16384
#define Tn 100
#define Vn 256
#define En 50
#define Hn 10
#define Ln 15
#define PROW 12  // padded hidden dim (multiple of 4 lanes x 3 units)

typedef float v2f __attribute__((ext_vector_type(2)));

// quad_perm DPP controls: xor1={1,0,3,2}, xor2={2,3,0,1}, xor3={3,2,1,0}
#define QP_X1 0xB1
#define QP_X2 0x4E
#define QP_X3 0x1B
#define DPPF(v, ctrl) \
    __int_as_float(__builtin_amdgcn_mov_dpp(__float_as_int(v), (ctrl), 0xF, 0xF, true))

__device__ __forceinline__ float tanh_fast(float x) {
    // tanh(x) = 1 - 2/(exp2(2x/ln2) + 1); clamp so exp can't overflow.
    float xc = fminf(fmaxf(x, -8.f), 8.f);
    float e  = __builtin_amdgcn_exp2f(xc * 2.8853900817779268f);
    float r  = __builtin_amdgcn_rcpf(e + 1.f);
    return __builtin_fmaf(-2.f, r, 1.f);
}

// Kernel 1: P[v][j] = emb[v]·Wx[:,j] + b_rnn[j], fp32, pads (j>=10) = 0.
__global__ void precompute_P(const float* __restrict__ emb,
                             const float* __restrict__ Wx,
                             const float* __restrict__ b_rnn,
                             float* __restrict__ P) {
    int tid = blockIdx.x * blockDim.x + threadIdx.x;
    if (tid >= Vn * PROW) return;
    int v = tid / PROW, j = tid - v * PROW;
    float acc = 0.f;
    if (j < Hn) {
        acc = b_rnn[j];
        #pragma unroll 5
        for (int k = 0; k < En; ++k)
            acc = __builtin_fmaf(emb[v * En + k], Wx[k * Hn + j], acc);
    }
    P[tid] = acc;
}

// Kernel 2: recurrence. Quad of 4 lanes per batch element; lane q owns
// hidden units j = 3q .. 3q+2 (j in [10,12) are exact-zero pads).
__global__ __launch_bounds__(256) void rnn_fwd(
    const int* __restrict__ x,
    const float* __restrict__ P,
    const float* __restrict__ Wh,
    const float* __restrict__ Wd,
    const float* __restrict__ bd,
    const float* __restrict__ drop,
    float* __restrict__ out) {
    __shared__ float Pl[Vn * PROW];  // 12 KB

    // Stage P: 3072 floats = 768 float4, 256 threads x 3.
    {
        const float4* Pg = (const float4*)P;
        float4* Ps = (float4*)Pl;
        #pragma unroll
        for (int i = 0; i < 3; ++i)
            Ps[i * 256 + threadIdx.x] = Pg[i * 256 + threadIdx.x];
    }

    const int g  = blockIdx.x * 256 + threadIdx.x;
    const int b  = g >> 2;        // batch element
    const int q  = g & 3;         // quad sub-lane
    const int j0 = 3 * q;         // first owned hidden unit

    // Wh fragments, ordered by DPP-source: whv/whs[m][rp] multiplies the
    // value h_{js} owned by lane q^m at slot rp (js = 3*(q^m)+rp), feeding
    // owned units j0+0/1 (v2f) and j0+2 (scalar). Pads -> exact 0 weight.
    v2f  whv[4][3];
    float whs[4][3];
    #pragma unroll
    for (int m = 0; m < 4; ++m) {
        int qs = q ^ m;
        #pragma unroll
        for (int rp = 0; rp < 3; ++rp) {
            int js  = 3 * qs + rp;
            int jss = js < Hn ? js : 0;  // safe address, value zeroed below
            float w0 = Wh[jss * Hn + (j0 + 0 < Hn ? j0 + 0 : 0)];
            float w1 = Wh[jss * Hn + (j0 + 1 < Hn ? j0 + 1 : 0)];
            float w2 = Wh[jss * Hn + (j0 + 2 < Hn ? j0 + 2 : 0)];
            bool oks = js < Hn;
            v2f wv;
            wv.x = (oks && j0 + 0 < Hn) ? w0 : 0.f;
            wv.y = (oks && j0 + 1 < Hn) ? w1 : 0.f;
            whv[m][rp] = wv;
            whs[m][rp] = (oks && j0 + 2 < Hn) ? w2 : 0.f;
        }
    }
    __syncthreads();

    const int* xb = x + b * Tn;  // 400 B/row -> 16B aligned

    v2f  hv = {0.f, 0.f};  // owned h: j0, j0+1
    float hs = 0.f;        // owned h: j0+2

    int4 xi = *(const int4*)xb;
    for (int c = 0; c < Tn / 4; ++c) {
        int4 xin = (c + 1 < Tn / 4) ? ((const int4*)xb)[c + 1] : xi;
        int xs[4] = {xi.x, xi.y, xi.z, xi.w};
        #pragma unroll
        for (int u = 0; u < 4; ++u) {
            const float* Pr = &Pl[xs[u] * PROW + j0];
            v2f  pv;
            pv.x = Pr[0];
            pv.y = Pr[1];
            float ps = Pr[2];

            // Gather the full h vector from the quad via DPP (9 ops).
            float hsrc[4][3];
            hsrc[0][0] = hv.x;            hsrc[0][1] = hv.y;            hsrc[0][2] = hs;
            hsrc[1][0] = DPPF(hv.x, QP_X1); hsrc[1][1] = DPPF(hv.y, QP_X1); hsrc[1][2] = DPPF(hs, QP_X1);
            hsrc[2][0] = DPPF(hv.x, QP_X2); hsrc[2][1] = DPPF(hv.y, QP_X2); hsrc[2][2] = DPPF(hs, QP_X2);
            hsrc[3][0] = DPPF(hv.x, QP_X3); hsrc[3][1] = DPPF(hv.y, QP_X3); hsrc[3][2] = DPPF(hs, QP_X3);

            #pragma unroll
            for (int m = 0; m < 4; ++m)
                #pragma unroll
                for (int rp = 0; rp < 3; ++rp) {
                    v2f hb = {hsrc[m][rp], hsrc[m][rp]};
                    pv += hb * whv[m][rp];
                    ps = __builtin_fmaf(hsrc[m][rp], whs[m][rp], ps);
                }

            hv.x = tanh_fast(pv.x);
            hv.y = tanh_fast(pv.y);
            hs   = tanh_fast(ps);
        }
        xi = xin;
    }

    // Epilogue: dropout, quad-gather hd, dense over this lane's l-slice.
    float hd[3];
    {
        float hown[3] = {hv.x, hv.y, hs};
        #pragma unroll
        for (int r = 0; r < 3; ++r) {
            int j   = j0 + r;
            int jdi = b * Hn + (j < Hn ? j : Hn - 1);  // safe address
            float d = drop[jdi];
            hd[r] = (j < Hn) ? hown[r] * d : 0.f;
        }
    }
    float hdsrc[4][3];
    hdsrc[0][0] = hd[0];            hdsrc[0][1] = hd[1];            hdsrc[0][2] = hd[2];
    hdsrc[1][0] = DPPF(hd[0], QP_X1); hdsrc[1][1] = DPPF(hd[1], QP_X1); hdsrc[1][2] = DPPF(hd[2], QP_X1);
    hdsrc[2][0] = DPPF(hd[0], QP_X2); hdsrc[2][1] = DPPF(hd[1], QP_X2); hdsrc[2][2] = DPPF(hd[2], QP_X2);
    hdsrc[3][0] = DPPF(hd[0], QP_X3); hdsrc[3][1] = DPPF(hd[1], QP_X3); hdsrc[3][2] = DPPF(hd[2], QP_X3);

    const int l0   = q * 4;
    const int lcnt = (q == 3) ? 3 : 4;
    #pragma unroll
    for (int li = 0; li < 4; ++li) {
        if (li >= lcnt) break;
        int l = l0 + li;
        float acc = bd[l];
        #pragma unroll
        for (int m = 0; m < 4; ++m)
            #pragma unroll
            for (int rp = 0; rp < 3; ++rp) {
                int js  = 3 * (q ^ m) + rp;
                int jss = js < Hn ? js : 0;        // hdsrc is 0 for pads
                acc = __builtin_fmaf(hdsrc[m][rp], Wd[jss * Ln + l], acc);
            }
        out[b * Ln + l] = acc;
    }
}

extern "C" void kernel_launch(void* const* d_in, const int* in_sizes, int n_in,
                              void* d_out, int out_size, void* d_ws, size_t ws_size,
                              hipStream_t stream) {
    const int*   x      = (const int*)d_in[0];
    const float* emb    = (const float*)d_in[1];
    const float* Wx     = (const float*)d_in[2];
    const float* Wh     = (const float*)d_in[3];
    const float* b_rnn  = (const float*)d_in[4];
    const float* Wd     = (const float*)d_in[5];
    const float* bd     = (const float*)d_in[6];
    const float* drop   = (const float*)d_in[7];
    float*       out    = (float*)d_out;

    float* P = (float*)d_ws;  // Vn*PROW*4 = 12288 bytes

    precompute_P<<<(Vn * PROW + 255) / 256, 256, 0, stream>>>(emb, Wx, b_rnn, P);
    // Bn*4 lanes / 256 = 256 blocks -> 1 block/CU, 4 waves -> 1 wave/SIMD.
    rnn_fwd<<<(Bn * 4) / 256, 256, 0, stream>>>(x, P, Wh, Wd, bd, drop, out);
}

// Round 4
// 88.761 us; speedup vs baseline: 1.2476x; 1.0249x over previous
//
#include <hip/hip_runtime.h>
#include <hip/hip_bf16.h>

// CharRNN: B=16384, T=100, V=256, E=50, H=10, L=15 — float tensors fp32.
// R4: single fused kernel. Phase A: each block stages emb+Wx(+b) into LDS
// and computes the P table (P[v][j] = emb[v]·Wx[:,j] + b_rnn[j], 256x12
// zero-padded) directly in LDS — removes the separate precompute dispatch
// and the P global round-trip (was ~2-4 us of the ~8 us controllable time).
// Phase B: quad-lane recurrence (4 lanes per batch element, 3 hidden units
// each, DPP quad_perm h-exchange) — unchanged from R3 except clamp -> med3.

#define Bn 16384
#define Tn 100
#define Vn 256
#define En 50
#define Hn 10
#define Ln 15
#define PROW 12  // padded hidden dim (4 lanes x 3 units)

typedef float v2f __attribute__((ext_vector_type(2)));

// quad_perm DPP controls: xor1={1,0,3,2}, xor2={2,3,0,1}, xor3={3,2,1,0}
#define QP_X1 0xB1
#define QP_X2 0x4E
#define QP_X3 0x1B
#define DPPF(v, ctrl) \
    __int_as_float(__builtin_amdgcn_mov_dpp(__float_as_int(v), (ctrl), 0xF, 0xF, true))

__device__ __forceinline__ float tanh_fast(float x) {
    // tanh(x) = 1 - 2/(exp2(2x/ln2) + 1).
    // |pre| is bounded ~5 here (|h|<=1, Wh ~N(0,0.1)); med3 clamp at +-8 is
    // pure safety against exp overflow, 1 instr (v_med3_f32).
    float xc = __builtin_amdgcn_fmed3f(x, -8.f, 8.f);
    float e  = __builtin_amdgcn_exp2f(xc * 2.8853900817779268f);
    float r  = __builtin_amdgcn_rcpf(e + 1.f);
    return __builtin_fmaf(-2.f, r, 1.f);
}

__global__ __launch_bounds__(256) void rnn_fused(
    const int* __restrict__ x,
    const float* __restrict__ emb,
    const float* __restrict__ Wx,
    const float* __restrict__ b_rnn,
    const float* __restrict__ Wh,
    const float* __restrict__ Wd,
    const float* __restrict__ bd,
    const float* __restrict__ drop,
    float* __restrict__ out) {
    __shared__ float embL[Vn * En];        // 51.2 KB
    __shared__ float WxL[(En + 1) * PROW]; // 2.45 KB: rows 0..49 = Wx (padded), row 50 = b_rnn (padded)
    __shared__ float Pl[Vn * PROW];        // 12 KB

    const int tid = threadIdx.x;

    // ---- Stage emb (coalesced float4: 3200 x 16B over 256 threads) ----
    {
        const float4* Eg = (const float4*)emb;
        float4* Es = (float4*)embL;
        #pragma unroll
        for (int i = 0; i < 13; ++i) {
            int idx = i * 256 + tid;
            if (idx < (Vn * En) / 4) Es[idx] = Eg[idx];
        }
    }
    // ---- Stage Wx padded to 12 + bias row (612 entries) ----
    for (int i = tid; i < (En + 1) * PROW; i += 256) {
        int k = i / PROW, j = i - k * PROW;
        float v = 0.f;
        if (j < Hn) v = (k < En) ? Wx[k * Hn + j] : b_rnn[j];
        WxL[i] = v;
    }
    __syncthreads();

    // ---- Phase A: thread v computes P row v into Pl (LDS-broadcast Wx) ----
    {
        const int v = tid;
        v2f acc[PROW / 2];
        {
            const v2f* brow = (const v2f*)(WxL + En * PROW);
            #pragma unroll
            for (int j2 = 0; j2 < PROW / 2; ++j2) acc[j2] = brow[j2];
        }
        const v2f* er = (const v2f*)(embL + v * En);  // 25 x float2 (8B aligned)
        #pragma unroll 5
        for (int k2 = 0; k2 < En / 2; ++k2) {
            v2f e2 = er[k2];
            const v2f* w0 = (const v2f*)(WxL + (2 * k2) * PROW);
            const v2f* w1 = w0 + PROW / 2;
            v2f ex = {e2.x, e2.x}, ey = {e2.y, e2.y};
            #pragma unroll
            for (int j2 = 0; j2 < PROW / 2; ++j2) {
                acc[j2] += ex * w0[j2];
                acc[j2] += ey * w1[j2];
            }
        }
        v2f* Pr = (v2f*)(Pl + v * PROW);
        #pragma unroll
        for (int j2 = 0; j2 < PROW / 2; ++j2) Pr[j2] = acc[j2];
    }

    // ---- Per-lane Wh fragments (global scalar loads, L2-resident) ----
    const int g  = blockIdx.x * 256 + tid;
    const int b  = g >> 2;   // batch element
    const int q  = g & 3;    // quad sub-lane
    const int j0 = 3 * q;    // first owned hidden unit

    v2f   whv[4][3];
    float whs[4][3];
    #pragma unroll
    for (int m = 0; m < 4; ++m) {
        int qs = q ^ m;
        #pragma unroll
        for (int rp = 0; rp < 3; ++rp) {
            int js  = 3 * qs + rp;
            int jss = js < Hn ? js : 0;  // safe address, value zeroed below
            float w0 = Wh[jss * Hn + (j0 + 0 < Hn ? j0 + 0 : 0)];
            float w1 = Wh[jss * Hn + (j0 + 1 < Hn ? j0 + 1 : 0)];
            float w2 = Wh[jss * Hn + (j0 + 2 < Hn ? j0 + 2 : 0)];
            bool oks = js < Hn;
            v2f wv;
            wv.x = (oks && j0 + 0 < Hn) ? w0 : 0.f;
            wv.y = (oks && j0 + 1 < Hn) ? w1 : 0.f;
            whv[m][rp] = wv;
            whs[m][rp] = (oks && j0 + 2 < Hn) ? w2 : 0.f;
        }
    }
    __syncthreads();

    // ---- Phase B: the recurrence ----
    const int* xb = x + b * Tn;  // 400 B/row -> 16B aligned

    v2f   hv = {0.f, 0.f};  // owned h: j0, j0+1
    float hs = 0.f;         // owned h: j0+2

    int4 xi = *(const int4*)xb;
    for (int c = 0; c < Tn / 4; ++c) {
        int4 xin = (c + 1 < Tn / 4) ? ((const int4*)xb)[c + 1] : xi;
        int xs[4] = {xi.x, xi.y, xi.z, xi.w};
        #pragma unroll
        for (int u = 0; u < 4; ++u) {
            const float* Pr = &Pl[xs[u] * PROW + j0];
            v2f pv;
            pv.x = Pr[0];
            pv.y = Pr[1];
            float ps = Pr[2];

            // Gather the full h vector from the quad via DPP (9 ops).
            float hsrc[4][3];
            hsrc[0][0] = hv.x;              hsrc[0][1] = hv.y;              hsrc[0][2] = hs;
            hsrc[1][0] = DPPF(hv.x, QP_X1); hsrc[1][1] = DPPF(hv.y, QP_X1); hsrc[1][2] = DPPF(hs, QP_X1);
            hsrc[2][0] = DPPF(hv.x, QP_X2); hsrc[2][1] = DPPF(hv.y, QP_X2); hsrc[2][2] = DPPF(hs, QP_X2);
            hsrc[3][0] = DPPF(hv.x, QP_X3); hsrc[3][1] = DPPF(hv.y, QP_X3); hsrc[3][2] = DPPF(hs, QP_X3);

            #pragma unroll
            for (int m = 0; m < 4; ++m)
                #pragma unroll
                for (int rp = 0; rp < 3; ++rp) {
                    v2f hb = {hsrc[m][rp], hsrc[m][rp]};
                    pv += hb * whv[m][rp];
                    ps = __builtin_fmaf(hsrc[m][rp], whs[m][rp], ps);
                }

            hv.x = tanh_fast(pv.x);
            hv.y = tanh_fast(pv.y);
            hs   = tanh_fast(ps);
        }
        xi = xin;
    }

    // ---- Epilogue: dropout, quad-gather hd, dense over this lane's l-slice ----
    float hd[3];
    {
        float hown[3] = {hv.x, hv.y, hs};
        #pragma unroll
        for (int r = 0; r < 3; ++r) {
            int j   = j0 + r;
            int jdi = b * Hn + (j < Hn ? j : Hn - 1);  // safe address
            float d = drop[jdi];
            hd[r] = (j < Hn) ? hown[r] * d : 0.f;
        }
    }
    float hdsrc[4][3];
    hdsrc[0][0] = hd[0];              hdsrc[0][1] = hd[1];              hdsrc[0][2] = hd[2];
    hdsrc[1][0] = DPPF(hd[0], QP_X1); hdsrc[1][1] = DPPF(hd[1], QP_X1); hdsrc[1][2] = DPPF(hd[2], QP_X1);
    hdsrc[2][0] = DPPF(hd[0], QP_X2); hdsrc[2][1] = DPPF(hd[1], QP_X2); hdsrc[2][2] = DPPF(hd[2], QP_X2);
    hdsrc[3][0] = DPPF(hd[0], QP_X3); hdsrc[3][1] = DPPF(hd[1], QP_X3); hdsrc[3][2] = DPPF(hd[2], QP_X3);

    const int l0   = q * 4;
    const int lcnt = (q == 3) ? 3 : 4;
    #pragma unroll
    for (int li = 0; li < 4; ++li) {
        if (li >= lcnt) break;
        int l = l0 + li;
        float acc = bd[l];
        #pragma unroll
        for (int m = 0; m < 4; ++m)
            #pragma unroll
            for (int rp = 0; rp < 3; ++rp) {
                int js  = 3 * (q ^ m) + rp;
                int jss = js < Hn ? js : 0;  // hdsrc is 0 for pads
                acc = __builtin_fmaf(hdsrc[m][rp], Wd[jss * Ln + l], acc);
            }
        out[b * Ln + l] = acc;
    }
}

extern "C" void kernel_launch(void* const* d_in, const int* in_sizes, int n_in,
                              void* d_out, int out_size, void* d_ws, size_t ws_size,
                              hipStream_t stream) {
    const int*   x      = (const int*)d_in[0];
    const float* emb    = (const float*)d_in[1];
    const float* Wx     = (const float*)d_in[2];
    const float* Wh     = (const float*)d_in[3];
    const float* b_rnn  = (const float*)d_in[4];
    const float* Wd     = (const float*)d_in[5];
    const float* bd     = (const float*)d_in[6];
    const float* drop   = (const float*)d_in[7];
    float*       out    = (float*)d_out;
    (void)d_ws; (void)ws_size;

    // 65536 lanes / 256 = 256 blocks -> 1 block/CU, 4 waves -> 1 wave/SIMD.
    rnn_fused<<<(Bn * 4) / 256, 256, 0, stream>>>(x, emb, Wx, b_rnn, Wh, Wd, bd, drop, out);
}

// Round 5
// 87.373 us; speedup vs baseline: 1.2674x; 1.0159x over previous
//
#include <hip/hip_runtime.h>
#include <hip/hip_bf16.h>

// CharRNN: B=16384, T=100, V=256, E=50, H=10, L=15 — float tensors fp32.
// R5: fused kernel, three issue-count cuts vs R4:
//  (1) tanh clamp removed — exp2-based tanh saturates correctly at +-inf.
//  (2) lambda = 2/ln2 folded into P and Wh fragments: per-step mul removed.
//  (3) Phase A reads Wx/b_rnn via wave-uniform (SGPR) loads — the 300
//      LDS broadcast reads of the Wx tile are gone (only emb-row ds_reads).
// Phase B: quad-lane recurrence (4 lanes/batch elem, 3 hidden units each,
// DPP quad_perm h-exchange), 1024 waves -> 1 wave on each of 1024 SIMDs.

#define Bn 16384
#define Tn 100
#define Vn 256
#define En 50
#define Hn 10
#define Ln 15
#define PROW 12  // padded hidden dim (4 lanes x 3 units)
#define LAMBDA 2.8853900817779268f  // 2/ln2, folded into P and Wh

typedef float v2f __attribute__((ext_vector_type(2)));

// quad_perm DPP controls: xor1={1,0,3,2}, xor2={2,3,0,1}, xor3={3,2,1,0}
#define QP_X1 0xB1
#define QP_X2 0x4E
#define QP_X3 0x1B
#define DPPF(v, ctrl) \
    __int_as_float(__builtin_amdgcn_mov_dpp(__float_as_int(v), (ctrl), 0xF, 0xF, true))

// Input is pre-scaled by LAMBDA: tanh(x) = 1 - 2/(exp2(lambda*x) + 1).
// No clamp needed: exp2(+big)=inf -> rcp=0 -> +1; exp2(-big)=0 -> rcp(1)=1 -> -1.
__device__ __forceinline__ float tanh_scaled(float xs) {
    float e = __builtin_amdgcn_exp2f(xs);
    float r = __builtin_amdgcn_rcpf(e + 1.f);
    return __builtin_fmaf(-2.f, r, 1.f);
}

__global__ __launch_bounds__(256) void rnn_fused(
    const int* __restrict__ x,
    const float* __restrict__ emb,
    const float* __restrict__ Wx,
    const float* __restrict__ b_rnn,
    const float* __restrict__ Wh,
    const float* __restrict__ Wd,
    const float* __restrict__ bd,
    const float* __restrict__ drop,
    float* __restrict__ out) {
    __shared__ float embL[Vn * En];  // 51.2 KB
    __shared__ float Pl[Vn * PROW];  // 12 KB

    const int tid = threadIdx.x;

    // ---- Stage emb (coalesced float4: 3200 x 16B over 256 threads) ----
    {
        const float4* Eg = (const float4*)emb;
        float4* Es = (float4*)embL;
        #pragma unroll
        for (int i = 0; i < 13; ++i) {
            int idx = i * 256 + tid;
            if (idx < (Vn * En) / 4) Es[idx] = Eg[idx];
        }
    }
    __syncthreads();

    // ---- Phase A: thread v computes P row v into Pl.
    // Wx/b_rnn indices are thread-uniform -> compiler emits s_load (SGPR
    // operands on the FMAs); only the emb row comes through the LDS pipe.
    {
        const int v = tid;
        v2f acc[5];
        #pragma unroll
        for (int j2 = 0; j2 < 5; ++j2) {
            v2f a; a.x = b_rnn[2 * j2]; a.y = b_rnn[2 * j2 + 1];
            acc[j2] = a;
        }
        const v2f* er = (const v2f*)(embL + v * En);  // 25 x float2, 8B aligned
        #pragma unroll 5
        for (int k2 = 0; k2 < En / 2; ++k2) {
            v2f e2 = er[k2];
            v2f ex = {e2.x, e2.x}, ey = {e2.y, e2.y};
            #pragma unroll
            for (int j2 = 0; j2 < 5; ++j2) {
                v2f w0; w0.x = Wx[(2 * k2) * Hn + 2 * j2];     w0.y = Wx[(2 * k2) * Hn + 2 * j2 + 1];
                v2f w1; w1.x = Wx[(2 * k2 + 1) * Hn + 2 * j2]; w1.y = Wx[(2 * k2 + 1) * Hn + 2 * j2 + 1];
                acc[j2] += ex * w0;
                acc[j2] += ey * w1;
            }
        }
        float* Pr = Pl + v * PROW;
        #pragma unroll
        for (int j2 = 0; j2 < 5; ++j2) {
            Pr[2 * j2]     = acc[j2].x * LAMBDA;  // lambda folded into P
            Pr[2 * j2 + 1] = acc[j2].y * LAMBDA;
        }
        Pr[10] = 0.f;
        Pr[11] = 0.f;
    }

    // ---- Per-lane Wh fragments (global scalar loads, L2-resident),
    //      pre-scaled by LAMBDA. Pads -> exact 0 weight.
    const int g  = blockIdx.x * 256 + tid;
    const int b  = g >> 2;   // batch element
    const int q  = g & 3;    // quad sub-lane
    const int j0 = 3 * q;    // first owned hidden unit

    v2f   whv[4][3];
    float whs[4][3];
    #pragma unroll
    for (int m = 0; m < 4; ++m) {
        int qs = q ^ m;
        #pragma unroll
        for (int rp = 0; rp < 3; ++rp) {
            int js  = 3 * qs + rp;
            int jss = js < Hn ? js : 0;  // safe address, value zeroed below
            float w0 = Wh[jss * Hn + (j0 + 0 < Hn ? j0 + 0 : 0)];
            float w1 = Wh[jss * Hn + (j0 + 1 < Hn ? j0 + 1 : 0)];
            float w2 = Wh[jss * Hn + (j0 + 2 < Hn ? j0 + 2 : 0)];
            bool oks = js < Hn;
            v2f wv;
            wv.x = (oks && j0 + 0 < Hn) ? w0 * LAMBDA : 0.f;
            wv.y = (oks && j0 + 1 < Hn) ? w1 * LAMBDA : 0.f;
            whv[m][rp] = wv;
            whs[m][rp] = (oks && j0 + 2 < Hn) ? w2 * LAMBDA : 0.f;
        }
    }
    __syncthreads();

    // ---- Phase B: the recurrence (h is the true tanh output, unscaled;
    //      the lambda scale rides on P and the Wh fragments). ----
    const int* xb = x + b * Tn;  // 400 B/row -> 16B aligned

    v2f   hv = {0.f, 0.f};  // owned h: j0, j0+1
    float hs = 0.f;         // owned h: j0+2

    int4 xi = *(const int4*)xb;
    for (int c = 0; c < Tn / 4; ++c) {
        int4 xin = (c + 1 < Tn / 4) ? ((const int4*)xb)[c + 1] : xi;
        int xs[4] = {xi.x, xi.y, xi.z, xi.w};
        #pragma unroll
        for (int u = 0; u < 4; ++u) {
            const float* Pr = &Pl[xs[u] * PROW + j0];
            v2f pv;
            pv.x = Pr[0];
            pv.y = Pr[1];
            float ps = Pr[2];

            // Gather the full h vector from the quad via DPP (9 ops).
            float hsrc[4][3];
            hsrc[0][0] = hv.x;              hsrc[0][1] = hv.y;              hsrc[0][2] = hs;
            hsrc[1][0] = DPPF(hv.x, QP_X1); hsrc[1][1] = DPPF(hv.y, QP_X1); hsrc[1][2] = DPPF(hs, QP_X1);
            hsrc[2][0] = DPPF(hv.x, QP_X2); hsrc[2][1] = DPPF(hv.y, QP_X2); hsrc[2][2] = DPPF(hs, QP_X2);
            hsrc[3][0] = DPPF(hv.x, QP_X3); hsrc[3][1] = DPPF(hv.y, QP_X3); hsrc[3][2] = DPPF(hs, QP_X3);

            #pragma unroll
            for (int m = 0; m < 4; ++m)
                #pragma unroll
                for (int rp = 0; rp < 3; ++rp) {
                    v2f hb = {hsrc[m][rp], hsrc[m][rp]};
                    pv += hb * whv[m][rp];
                    ps = __builtin_fmaf(hsrc[m][rp], whs[m][rp], ps);
                }

            hv.x = tanh_scaled(pv.x);
            hv.y = tanh_scaled(pv.y);
            hs   = tanh_scaled(ps);
        }
        xi = xin;
    }

    // ---- Epilogue: dropout, quad-gather hd, dense over this lane's l-slice ----
    float hd[3];
    {
        float hown[3] = {hv.x, hv.y, hs};
        #pragma unroll
        for (int r = 0; r < 3; ++r) {
            int j   = j0 + r;
            int jdi = b * Hn + (j < Hn ? j : Hn - 1);  // safe address
            float d = drop[jdi];
            hd[r] = (j < Hn) ? hown[r] * d : 0.f;
        }
    }
    float hdsrc[4][3];
    hdsrc[0][0] = hd[0];              hdsrc[0][1] = hd[1];              hdsrc[0][2] = hd[2];
    hdsrc[1][0] = DPPF(hd[0], QP_X1); hdsrc[1][1] = DPPF(hd[1], QP_X1); hdsrc[1][2] = DPPF(hd[2], QP_X1);
    hdsrc[2][0] = DPPF(hd[0], QP_X2); hdsrc[2][1] = DPPF(hd[1], QP_X2); hdsrc[2][2] = DPPF(hd[2], QP_X2);
    hdsrc[3][0] = DPPF(hd[0], QP_X3); hdsrc[3][1] = DPPF(hd[1], QP_X3); hdsrc[3][2] = DPPF(hd[2], QP_X3);

    const int l0   = q * 4;
    const int lcnt = (q == 3) ? 3 : 4;
    #pragma unroll
    for (int li = 0; li < 4; ++li) {
        if (li >= lcnt) break;
        int l = l0 + li;
        float acc = bd[l];
        #pragma unroll
        for (int m = 0; m < 4; ++m)
            #pragma unroll
            for (int rp = 0; rp < 3; ++rp) {
                int js  = 3 * (q ^ m) + rp;
                int jss = js < Hn ? js : 0;  // hdsrc is 0 for pads
                acc = __builtin_fmaf(hdsrc[m][rp], Wd[jss * Ln + l], acc);
            }
        out[b * Ln + l] = acc;
    }
}

extern "C" void kernel_launch(void* const* d_in, const int* in_sizes, int n_in,
                              void* d_out, int out_size, void* d_ws, size_t ws_size,
                              hipStream_t stream) {
    const int*   x      = (const int*)d_in[0];
    const float* emb    = (const float*)d_in[1];
    const float* Wx     = (const float*)d_in[2];
    const float* Wh     = (const float*)d_in[3];
    const float* b_rnn  = (const float*)d_in[4];
    const float* Wd     = (const float*)d_in[5];
    const float* bd     = (const float*)d_in[6];
    const float* drop   = (const float*)d_in[7];
    float*       out    = (float*)d_out;
    (void)d_ws; (void)ws_size;

    // 65536 lanes / 256 = 256 blocks -> 1 block/CU, 4 waves -> 1 wave/SIMD.
    rnn_fused<<<(Bn * 4) / 256, 256, 0, stream>>>(x, emb, Wx, b_rnn, Wh, Wd, bd, drop, out);
}